// Round 11
// baseline (385.622 us; speedup 1.0000x reference)
//
#include <hip/hip_runtime.h>
#include <hip/hip_bf16.h>

#define DEV __device__ __forceinline__

DEV float fexp2(float x) {
#if __has_builtin(__builtin_amdgcn_exp2f)
  return __builtin_amdgcn_exp2f(x);
#else
  return exp2f(x);
#endif
}
DEV float frcp(float x) {
#if __has_builtin(__builtin_amdgcn_rcpf)
  return __builtin_amdgcn_rcpf(x);
#else
  return 1.0f / x;
#endif
}
DEV float rdlanef(float v, int l) {
#if __has_builtin(__builtin_amdgcn_readlane)
  return __uint_as_float(__builtin_amdgcn_readlane(__float_as_uint(v), l));
#else
  return __shfl(v, l);
#endif
}

// 2*log2(e): folds tanh's e^{2x} into a single v_exp_f32 (2^x)
#define K_C2LOG2E 2.8853900817779268f

// ---------------------------------------------------------------------------
// prep1: fused table chain. Blocks 0..22: per-v chain dr->c1->branches->T4.
// Block 23: rt pad row, W5 = fc5@c41_w, bias_fc.
// ---------------------------------------------------------------------------
__global__ void __launch_bounds__(256)
prep1(const float* __restrict__ emb,
      const float* __restrict__ dr_w, const float* __restrict__ dr_b,
      const float* __restrict__ c1_w, const float* __restrict__ c1_b,
      const float* __restrict__ w11, const float* __restrict__ b11,
      const float* __restrict__ w12, const float* __restrict__ b12,
      const float* __restrict__ w21, const float* __restrict__ b21,
      const float* __restrict__ w22, const float* __restrict__ b22,
      const float* __restrict__ w31, const float* __restrict__ b31,
      const float* __restrict__ w32, const float* __restrict__ b32,
      const float* __restrict__ fc_w, const float* __restrict__ fc_b,
      const float* __restrict__ c41_w, const float* __restrict__ c41_b,
      float* __restrict__ rt_ext, float* __restrict__ T4,
      float* __restrict__ W5, float* __restrict__ bias_fc)
{
  const int v = blockIdx.x, tid = threadIdx.x;
  if (v < 23) {
    __shared__ float A[64], Rt[64], X2[3][64];
    const int c = tid & 63;
    if (tid < 64) {
      float acc = dr_b[c];
      #pragma unroll 8
      for (int e = 0; e < 32; ++e) {
        const float4 wv = *(const float4*)&dr_w[c * 128 + 4 * e];
        const float4 ev = *(const float4*)&emb[v * 128 + 4 * e];
        acc = fmaf(wv.x, ev.x, acc); acc = fmaf(wv.y, ev.y, acc);
        acc = fmaf(wv.z, ev.z, acc); acc = fmaf(wv.w, ev.w, acc);
      }
      A[c] = acc;
    }
    __syncthreads();
    if (tid < 64) {
      float acc = c1_b[c];
      for (int m = 0; m < 64; ++m) acc = fmaf(c1_w[c * 64 + m], A[m], acc);
      Rt[c] = acc;
      rt_ext[v * 64 + c] = acc;
    }
    for (int br = 0; br < 3; ++br) {
      const float* w1 = (br == 0) ? w11 : (br == 1) ? w21 : w31;
      const float* b1 = (br == 0) ? b11 : (br == 1) ? b21 : b31;
      const float* w2 = (br == 0) ? w12 : (br == 1) ? w22 : w32;
      const float* b2 = (br == 0) ? b12 : (br == 1) ? b22 : b32;
      __syncthreads();
      if (tid < 64) {
        float acc = b1[c];
        for (int m = 0; m < 64; ++m) acc = fmaf(w1[c * 64 + m], Rt[m], acc);
        A[c] = acc;
      }
      __syncthreads();
      if (tid < 64) {
        float acc = b2[c];
        for (int m = 0; m < 64; ++m) acc = fmaf(w2[c * 64 + m], A[m], acc);
        X2[br][c] = acc;
      }
    }
    __syncthreads();
    if (tid < 64) {
      float acc = 0.f;
      for (int m = 0; m < 64; ++m) acc = fmaf(fc_w[c * 320 + m],       Rt[m],    acc);
      for (int m = 0; m < 64; ++m) acc = fmaf(fc_w[c * 320 + 64 + m],  X2[0][m], acc);
      for (int m = 0; m < 64; ++m) acc = fmaf(fc_w[c * 320 + 128 + m], X2[1][m], acc);
      for (int m = 0; m < 64; ++m) acc = fmaf(fc_w[c * 320 + 192 + m], X2[2][m], acc);
      T4[v * 64 + c] = acc;
    }
  } else {
    if (tid < 64) rt_ext[23 * 64 + tid] = -1e30f;   // maxpool -inf pad row
    const int m = tid & 63, c0 = (tid >> 6) * 16;
    float acc[16];
    #pragma unroll
    for (int r = 0; r < 16; ++r) acc[r] = 0.f;
    for (int q = 0; q < 64; ++q) {
      const float w = c41_w[q * 64 + m];
      #pragma unroll
      for (int r = 0; r < 16; ++r)
        acc[r] = fmaf(fc_w[(c0 + r) * 320 + 256 + q], w, acc[r]);
    }
    #pragma unroll
    for (int r = 0; r < 16; ++r) W5[(c0 + r) * 64 + m] = acc[r];
    if (tid < 64) {
      float a2 = fc_b[tid];
      for (int q = 0; q < 64; ++q) a2 = fmaf(fc_w[tid * 320 + 256 + q], c41_b[q], a2);
      bias_fc[tid] = a2;
    }
  }
}

// ---------------------------------------------------------------------------
// tab_T5G: blocks 0..3 = one cp1 k-slice each (staged in LDS, conflict-free):
//   T5[v][k][o] and G[k][m][o]. Block 4: bb.
// R8 version did 64 scattered 4B global reads per lane (uncoalesced) — now
// the k-slice is staged once and all inner reads are broadcast/consecutive.
// ---------------------------------------------------------------------------
__global__ void __launch_bounds__(256)
tab_T5G(const float* __restrict__ cp1_w, const float* __restrict__ cp1_b,
        const float* __restrict__ T4, const float* __restrict__ W5,
        const float* __restrict__ bias_fc,
        float* __restrict__ T5, float* __restrict__ G, float* __restrict__ bb)
{
  const int k = blockIdx.x, tid = threadIdx.x;
  if (k < 4) {
    __shared__ float slice[64 * 65];  // [c][o] padded: +1 kills write conflicts
    __shared__ float W5l[64 * 64];    // [c][m]
    __shared__ float T4l[23 * 64];
    for (int i = tid; i < 4096; i += 256) {
      const int o = i >> 6, c = i & 63;
      slice[c * 65 + o] = cp1_w[o * 256 + c * 4 + k];
    }
    for (int i = tid; i < 4096; i += 256) W5l[i] = W5[i];
    for (int i = tid; i < 1472; i += 256) T4l[i] = T4[i];
    __syncthreads();
    for (int i = tid; i < 1472; i += 256) {
      const int v = i >> 6, o = i & 63;       // v uniform per 64-group
      float acc = 0.f;
      for (int c = 0; c < 64; ++c)
        acc = fmaf(slice[c * 65 + o], T4l[v * 64 + c], acc);  // bcast T4l
      T5[v * 256 + k * 64 + o] = acc;
    }
    for (int i = tid; i < 4096; i += 256) {
      const int m = i >> 6, o = i & 63;       // m uniform per 64-group
      float acc = 0.f;
      for (int c = 0; c < 64; ++c)
        acc = fmaf(slice[c * 65 + o], W5l[c * 64 + m], acc);  // bcast W5l
      G[k * 4096 + m * 64 + o] = acc;
    }
  } else {
    if (tid < 64) {
      float acc = cp1_b[tid];
      for (int c = 0; c < 64; ++c) {
        const float* p = &cp1_w[tid * 256 + c * 4];
        acc = fmaf(p[0] + p[1] + p[2] + p[3], bias_fc[c], acc);
      }
      bb[tid] = acc;
    }
  }
}

// FP5[v3][k][o] = sum_m G[k][m][o] * max3(rt[a],rt[c],rt[d])[m], v3 base-24.
// One k-pair (h) per block; 32 v per block; 4-v register tiling per m.
__global__ void __launch_bounds__(256)
tab_FP5(const float* __restrict__ G, const float* __restrict__ rt_ext,
        float* __restrict__ FP5)
{
  __shared__ float Gl[2][64][64];   // 32KB: one k-pair of G
  __shared__ float rtl[24 * 64];    // 6KB
  const int tid = threadIdx.x, lane = tid & 63, wave = tid >> 6;
  const int h = blockIdx.x & 1;
  const int vbase = (blockIdx.x >> 1) * 32;
  for (int i = tid; i < 1536; i += 256) rtl[i] = rt_ext[i];
  for (int i = tid; i < 8192; i += 256) ((float*)Gl)[i] = G[h * 8192 + i];
  __syncthreads();
  for (int g = 0; g < 2; ++g) {
    const int j0 = vbase + wave * 8 + g * 4;
    float p[4];
    #pragma unroll
    for (int r = 0; r < 4; ++r) {
      const int v = j0 + r;
      const int a = v / 576, rem = v - a * 576, c = rem / 24, dd = rem - c * 24;
      p[r] = fmaxf(fmaxf(rtl[a * 64 + lane], rtl[c * 64 + lane]), rtl[dd * 64 + lane]);
    }
    float acc[4][2];
    #pragma unroll
    for (int r = 0; r < 4; ++r) { acc[r][0] = 0.f; acc[r][1] = 0.f; }
    #pragma unroll
    for (int m = 0; m < 64; ++m) {
      const float g0 = Gl[0][m][lane], g1 = Gl[1][m][lane];
      #pragma unroll
      for (int r = 0; r < 4; ++r) {
        const float pv = __shfl(p[r], m);
        acc[r][0] = fmaf(g0, pv, acc[r][0]);
        acc[r][1] = fmaf(g1, pv, acc[r][1]);
      }
    }
    #pragma unroll
    for (int r = 0; r < 4; ++r) {
      const int v = j0 + r;
      FP5[v * 256 + (2 * h + 0) * 64 + lane] = acc[r][0];
      FP5[v * 256 + (2 * h + 1) * 64 + lane] = acc[r][1];
    }
  }
}

// ---------------------------------------------------------------------------
// Main fused kernel. One block (512 thr = 8 waves) per batch element.
// R8 diagnosis: LDS-pipe-bound (VALUBusy 37%). This version:
//  - fused wt/wx matvec sharing a_in loads (halves matvec LDS b128s)
//  - softmax probs kept in static regs a1r/a2r per wave-row
//  - PV as outer-j loop: 1 LDS read per j + v_readlane broadcasts (VALU pipe)
//    => PV LDS ops/wave ~808 -> 75
// ---------------------------------------------------------------------------
__global__ void __launch_bounds__(512)
k_main(const int* __restrict__ x,
       const float* __restrict__ wt, const float* __restrict__ wx,
       const float* __restrict__ bh, const float* __restrict__ wa,
       const float* __restrict__ T5, const float* __restrict__ FP5,
       const float* __restrict__ bb, float* __restrict__ vv)
{
  __shared__ int x_lds[304];
  __shared__ __align__(16) float a_in_lds[75 * 64];   // 19200 B
  __shared__ __align__(16) float qt_lds[75 * 68];     // 20400 B
  __shared__ __align__(16) float kx_lds[75 * 65];     // 19500 B, stride-65
  __shared__ __align__(16) float tail_lds[75 * 12];   // 3600 B
  __shared__ float wa_lds[64];                        // total 64172 B

  const int tid = threadIdx.x, lane = tid & 63, wave = tid >> 6;
  const int b = blockIdx.x;

  for (int i = tid; i < 300; i += 512) x_lds[i] = x[b * 300 + i];
  if (tid < 64) wa_lds[tid] = wa[tid];
  __syncthreads();

  // ---- a_in[t][o] = bb + sum_k T5[x_l][k] + FP5[trip_l][k]
  {
    const float bbv = bb[lane];
    for (int t = wave; t < 75; t += 8) {
      float acc = bbv;
      #pragma unroll
      for (int k = 0; k < 4; ++k) {
        const int l = 4 * t + k;
        const int xa = (l == 0) ? 23 : x_lds[l - 1];
        const int xd = (l == 299) ? 23 : x_lds[l + 1];
        const int trip = (xa * 576 + x_lds[l] * 24 + xd) * 256;
        acc += T5[x_lds[l] * 256 + k * 64 + lane];
        acc += FP5[trip + k * 64 + lane];
      }
      a_in_lds[t * 64 + lane] = acc;
    }
  }
  __syncthreads();

  // ---- fused matvec: qt=(a_in@wt.T+bh)*K, kx=(a_in@wx.T)*K; share a-loads
  {
    float qacc[10], kacc[10];
    #pragma unroll
    for (int r = 0; r < 10; ++r) { qacc[r] = 0.f; kacc[r] = 0.f; }
    for (int c = 0; c < 4; ++c) {
      const float4 t0 = *(const float4*)&wt[lane * 64 + 16 * c];
      const float4 t1 = *(const float4*)&wt[lane * 64 + 16 * c + 4];
      const float4 t2 = *(const float4*)&wt[lane * 64 + 16 * c + 8];
      const float4 t3 = *(const float4*)&wt[lane * 64 + 16 * c + 12];
      const float4 x0 = *(const float4*)&wx[lane * 64 + 16 * c];
      const float4 x1 = *(const float4*)&wx[lane * 64 + 16 * c + 4];
      const float4 x2 = *(const float4*)&wx[lane * 64 + 16 * c + 8];
      const float4 x3 = *(const float4*)&wx[lane * 64 + 16 * c + 12];
      #pragma unroll
      for (int r = 0; r < 10; ++r) {
        const int i = wave + 8 * r;
        if (i < 75) {
          const float* arow = &a_in_lds[i * 64 + 16 * c];
          const float4 a0 = *(const float4*)&arow[0];
          const float4 a1 = *(const float4*)&arow[4];
          const float4 a2 = *(const float4*)&arow[8];
          const float4 a3 = *(const float4*)&arow[12];
          float q = qacc[r], kk = kacc[r];
          q = fmaf(t0.x, a0.x, q); q = fmaf(t0.y, a0.y, q);
          q = fmaf(t0.z, a0.z, q); q = fmaf(t0.w, a0.w, q);
          q = fmaf(t1.x, a1.x, q); q = fmaf(t1.y, a1.y, q);
          q = fmaf(t1.z, a1.z, q); q = fmaf(t1.w, a1.w, q);
          q = fmaf(t2.x, a2.x, q); q = fmaf(t2.y, a2.y, q);
          q = fmaf(t2.z, a2.z, q); q = fmaf(t2.w, a2.w, q);
          q = fmaf(t3.x, a3.x, q); q = fmaf(t3.y, a3.y, q);
          q = fmaf(t3.z, a3.z, q); q = fmaf(t3.w, a3.w, q);
          kk = fmaf(x0.x, a0.x, kk); kk = fmaf(x0.y, a0.y, kk);
          kk = fmaf(x0.z, a0.z, kk); kk = fmaf(x0.w, a0.w, kk);
          kk = fmaf(x1.x, a1.x, kk); kk = fmaf(x1.y, a1.y, kk);
          kk = fmaf(x1.z, a1.z, kk); kk = fmaf(x1.w, a1.w, kk);
          kk = fmaf(x2.x, a2.x, kk); kk = fmaf(x2.y, a2.y, kk);
          kk = fmaf(x2.z, a2.z, kk); kk = fmaf(x2.w, a2.w, kk);
          kk = fmaf(x3.x, a3.x, kk); kk = fmaf(x3.y, a3.y, kk);
          kk = fmaf(x3.z, a3.z, kk); kk = fmaf(x3.w, a3.w, kk);
          qacc[r] = q; kacc[r] = kk;
        }
      }
    }
    const float bhv = bh[lane];
    #pragma unroll
    for (int r = 0; r < 10; ++r) {
      const int i = wave + 8 * r;
      if (i < 75) {
        qt_lds[i * 68 + lane] = (qacc[r] + bhv) * K_C2LOG2E;
        kx_lds[i * 65 + lane] = kacc[r] * K_C2LOG2E;
      }
    }
  }
  __syncthreads();

  // ---- tail scores: S[i][64+jt], one lane per cell, bank-staggered d.
  for (int idx = tid; idx < 825; idx += 512) {
    const int i = idx / 11, jt = idx - i * 11;
    const float* qrow = &qt_lds[i * 68];
    const float* krow = &kx_lds[(64 + jt) * 65];
    float S = 0.f;
    #pragma unroll 8
    for (int dd = 0; dd < 64; ++dd) {
      const int d = (dd + lane) & 63;
      const float r = frcp(1.f + fexp2(qrow[d] + krow[d]));
      S = fmaf(wa_lds[d], r, S);
    }
    tail_lds[i * 12 + jt] = S;
  }
  __syncthreads();

  // ---- score+softmax for this wave's rows -> probs in static regs
  float a1r[10], a2r[10];
  #pragma unroll
  for (int r = 0; r < 10; ++r) { a1r[r] = 0.f; a2r[r] = 0.f; }
  {
    const float* krow = &kx_lds[lane * 65];
    #pragma unroll
    for (int r = 0; r < 10; ++r) {
      const int i = wave + 8 * r;
      if (i < 75) {
        float S1 = 0.f;
        #pragma unroll
        for (int q = 0; q < 16; ++q) {
          const float4 q4 = *(const float4*)&qt_lds[i * 68 + 4 * q];  // bcast
          const float4 w4 = *(const float4*)&wa_lds[4 * q];           // bcast
          float rr;
          rr = frcp(1.f + fexp2(q4.x + krow[4 * q + 0])); S1 = fmaf(w4.x, rr, S1);
          rr = frcp(1.f + fexp2(q4.y + krow[4 * q + 1])); S1 = fmaf(w4.y, rr, S1);
          rr = frcp(1.f + fexp2(q4.z + krow[4 * q + 2])); S1 = fmaf(w4.z, rr, S1);
          rr = frcp(1.f + fexp2(q4.w + krow[4 * q + 3])); S1 = fmaf(w4.w, rr, S1);
        }
        const float z1 = S1 * (-K_C2LOG2E);
        const float zt = (lane < 11) ? tail_lds[i * 12 + lane] * (-K_C2LOG2E) : -1e30f;
        float m = fmaxf(z1, zt);
        #pragma unroll
        for (int off = 32; off; off >>= 1) m = fmaxf(m, __shfl_xor(m, off));
        const float p1 = fexp2(z1 - m);
        const float p2 = (lane < 11) ? fexp2(zt - m) : 0.f;
        float s = p1 + p2;
        #pragma unroll
        for (int off = 32; off; off >>= 1) s += __shfl_xor(s, off);
        const float inv = frcp(s);
        a1r[r] = p1 * inv;
        a2r[r] = p2 * inv;
      }
    }
  }

  // ---- PV outer-j: 1 LDS read per j + readlane broadcasts (VALU pipe)
  {
    float acc[10];
    #pragma unroll
    for (int r = 0; r < 10; ++r) acc[r] = 0.f;
    for (int j = 0; j < 64; ++j) {          // j uniform -> readlane legal
      const float ajo = a_in_lds[j * 64 + lane];
      #pragma unroll
      for (int r = 0; r < 10; ++r)
        acc[r] = fmaf(rdlanef(a1r[r], j), ajo, acc[r]);
    }
    for (int j = 0; j < 11; ++j) {
      const float ajo = a_in_lds[(64 + j) * 64 + lane];
      #pragma unroll
      for (int r = 0; r < 10; ++r)
        acc[r] = fmaf(rdlanef(a2r[r], j), ajo, acc[r]);
    }
    #pragma unroll
    for (int r = 0; r < 10; ++r) {
      const int i = wave + 8 * r;
      if (i < 75) vv[b * 4800 + i * 64 + lane] = fmaxf(acc[r], 0.f);  // relu
    }
  }
}

// ---------------------------------------------------------------------------
// Tail: cp2 (k=5,s=5) -> flatten [960] -> m1 + relu -> m2. 1 batch per block;
// cp2 indexed o=idx&63 so vv_lds reads are wave-uniform broadcasts.
// ---------------------------------------------------------------------------
__global__ void __launch_bounds__(256)
k_tail(const float* __restrict__ vv,
       const float* __restrict__ cp2_w, const float* __restrict__ cp2_b,
       const float* __restrict__ m1_w, const float* __restrict__ m1_b,
       const float* __restrict__ m2_w, const float* __restrict__ m2_b,
       float* __restrict__ out)
{
  __shared__ __align__(16) float vv_lds[75 * 65];  // stride-65 pad
  __shared__ float g_lds[960];
  __shared__ float y_lds[100];
  const int tid = threadIdx.x, lane = tid & 63, wave = tid >> 6;
  const int b = blockIdx.x;

  for (int idx = tid; idx < 4800; idx += 256) {
    const int i = idx >> 6, d = idx & 63;
    vv_lds[i * 65 + d] = vv[b * 4800 + idx];
  }
  __syncthreads();
  for (int idx = tid; idx < 960; idx += 256) {
    const int s = idx >> 6, o = idx & 63;    // s uniform per 64-group
    float acc = cp2_b[o];
    for (int c = 0; c < 64; ++c) {
      const float* wrow = &cp2_w[(o * 64 + c) * 5];
      const float* vrow = &vv_lds[5 * s * 65 + c];   // bcast reads
      #pragma unroll
      for (int k = 0; k < 5; ++k)
        acc = fmaf(wrow[k], vrow[k * 65], acc);
    }
    g_lds[o * 15 + s] = acc;  // o*15+s matches reshape order
  }
  __syncthreads();

  for (int u = wave; u < 100; u += 4) {
    float acc0 = 0.f;
    #pragma unroll
    for (int it = 0; it < 15; ++it) {
      const int n = it * 64 + lane;
      acc0 = fmaf(m1_w[u * 960 + n], g_lds[n], acc0);
    }
    #pragma unroll
    for (int off = 32; off; off >>= 1) acc0 += __shfl_xor(acc0, off);
    if (lane == 0) y_lds[u] = fmaxf(acc0 + m1_b[u], 0.f);
  }
  __syncthreads();
  if (wave == 0) {
    float s = y_lds[lane] * m2_w[lane];
    if (lane < 36) s = fmaf(y_lds[lane + 64], m2_w[lane + 64], s);
    #pragma unroll
    for (int off = 32; off; off >>= 1) s += __shfl_xor(s, off);
    if (lane == 0) out[b] = s + m2_b[0];
  }
}

// ---------------------------------------------------------------------------
extern "C" void kernel_launch(void* const* d_in, const int* in_sizes, int n_in,
                              void* d_out, int out_size, void* d_ws, size_t ws_size,
                              hipStream_t stream) {
  (void)in_sizes; (void)n_in; (void)out_size; (void)ws_size;
  const int*   x     = (const int*)  d_in[0];
  const float* emb   = (const float*)d_in[1];
  const float* dr_w  = (const float*)d_in[2];
  const float* dr_b  = (const float*)d_in[3];
  const float* c1_w  = (const float*)d_in[4];
  const float* c1_b  = (const float*)d_in[5];
  const float* c11_w = (const float*)d_in[6];
  const float* c11_b = (const float*)d_in[7];
  const float* c12_w = (const float*)d_in[8];
  const float* c12_b = (const float*)d_in[9];
  const float* c21_w = (const float*)d_in[10];
  const float* c21_b = (const float*)d_in[11];
  const float* c22_w = (const float*)d_in[12];
  const float* c22_b = (const float*)d_in[13];
  const float* c31_w = (const float*)d_in[14];
  const float* c31_b = (const float*)d_in[15];
  const float* c32_w = (const float*)d_in[16];
  const float* c32_b = (const float*)d_in[17];
  const float* c41_w = (const float*)d_in[18];
  const float* c41_b = (const float*)d_in[19];
  const float* fc_w  = (const float*)d_in[20];
  const float* fc_b  = (const float*)d_in[21];
  const float* cp1_w = (const float*)d_in[22];
  const float* cp1_b = (const float*)d_in[23];
  const float* cp2_w = (const float*)d_in[24];
  const float* cp2_b = (const float*)d_in[25];
  const float* wt    = (const float*)d_in[26];
  const float* wx    = (const float*)d_in[27];
  const float* bh    = (const float*)d_in[28];
  const float* wa    = (const float*)d_in[29];
  // d_in[30] = ba: cancels in softmax, unused
  const float* m1_w  = (const float*)d_in[31];
  const float* m1_b  = (const float*)d_in[32];
  const float* m2_w  = (const float*)d_in[33];
  const float* m2_b  = (const float*)d_in[34];
  float* out = (float*)d_out;

  // workspace layout (floats)
  float* ws      = (float*)d_ws;
  float* rt_ext  = ws;                 // 24*64          = 1536
  float* T5      = ws + 1536;          // 23*4*64        = 5888
  float* bb      = ws + 7424;          // 64
  float* G       = ws + 7488;          // 4*64*64        = 16384
  float* bias_fc = ws + 23872;         // 64
  float* T4      = ws + 28352;         // 23*64          = 1472
  float* W5      = ws + 29824;         // 64*64          = 4096
  float* FP5     = ws + 33920;         // 13824*4*64     = 3538944
  float* vv      = ws + 3572864;       // 512*75*64      = 2457600  (total ~24.1 MB)

  prep1  <<<24, 256, 0, stream>>>(emb, dr_w, dr_b, c1_w, c1_b,
                                  c11_w, c11_b, c12_w, c12_b,
                                  c21_w, c21_b, c22_w, c22_b,
                                  c31_w, c31_b, c32_w, c32_b,
                                  fc_w, fc_b, c41_w, c41_b,
                                  rt_ext, T4, W5, bias_fc);
  tab_T5G<<<5, 256, 0, stream>>>(cp1_w, cp1_b, T4, W5, bias_fc, T5, G, bb);
  tab_FP5<<<864, 256, 0, stream>>>(G, rt_ext, FP5);
  k_main <<<512, 512, 0, stream>>>(x, wt, wx, bh, wa, T5, FP5, bb, vv);
  k_tail <<<512, 256, 0, stream>>>(vv, cp2_w, cp2_b, m1_w, m1_b, m2_w, m2_b, out);
}

// Round 12
// 327.552 us; speedup vs baseline: 1.1773x; 1.1773x over previous
//
#include <hip/hip_runtime.h>
#include <hip/hip_bf16.h>

#define DEV __device__ __forceinline__

DEV float fexp2(float x) {
#if __has_builtin(__builtin_amdgcn_exp2f)
  return __builtin_amdgcn_exp2f(x);
#else
  return exp2f(x);
#endif
}
DEV float frcp(float x) {
#if __has_builtin(__builtin_amdgcn_rcpf)
  return __builtin_amdgcn_rcpf(x);
#else
  return 1.0f / x;
#endif
}
DEV float rdlanef(float v, int l) {
#if __has_builtin(__builtin_amdgcn_readlane)
  return __uint_as_float(__builtin_amdgcn_readlane(__float_as_uint(v), l));
#else
  return __shfl(v, l);
#endif
}

// 2*log2(e): folds tanh's e^{2x} into a single v_exp_f32 (2^x)
#define K_C2LOG2E 2.8853900817779268f

// ---------------------------------------------------------------------------
// prep1: fused table chain. Blocks 0..22: per-v chain dr->c1->branches->T4.
// Block 23: rt pad row, W5 = fc5@c41_w, bias_fc.
// ---------------------------------------------------------------------------
__global__ void __launch_bounds__(256)
prep1(const float* __restrict__ emb,
      const float* __restrict__ dr_w, const float* __restrict__ dr_b,
      const float* __restrict__ c1_w, const float* __restrict__ c1_b,
      const float* __restrict__ w11, const float* __restrict__ b11,
      const float* __restrict__ w12, const float* __restrict__ b12,
      const float* __restrict__ w21, const float* __restrict__ b21,
      const float* __restrict__ w22, const float* __restrict__ b22,
      const float* __restrict__ w31, const float* __restrict__ b31,
      const float* __restrict__ w32, const float* __restrict__ b32,
      const float* __restrict__ fc_w, const float* __restrict__ fc_b,
      const float* __restrict__ c41_w, const float* __restrict__ c41_b,
      float* __restrict__ rt_ext, float* __restrict__ T4,
      float* __restrict__ W5, float* __restrict__ bias_fc)
{
  const int v = blockIdx.x, tid = threadIdx.x;
  if (v < 23) {
    __shared__ float A[64], Rt[64], X2[3][64];
    const int c = tid & 63;
    if (tid < 64) {
      float acc = dr_b[c];
      #pragma unroll 8
      for (int e = 0; e < 32; ++e) {
        const float4 wv = *(const float4*)&dr_w[c * 128 + 4 * e];
        const float4 ev = *(const float4*)&emb[v * 128 + 4 * e];
        acc = fmaf(wv.x, ev.x, acc); acc = fmaf(wv.y, ev.y, acc);
        acc = fmaf(wv.z, ev.z, acc); acc = fmaf(wv.w, ev.w, acc);
      }
      A[c] = acc;
    }
    __syncthreads();
    if (tid < 64) {
      float acc = c1_b[c];
      for (int m = 0; m < 64; ++m) acc = fmaf(c1_w[c * 64 + m], A[m], acc);
      Rt[c] = acc;
      rt_ext[v * 64 + c] = acc;
    }
    for (int br = 0; br < 3; ++br) {
      const float* w1 = (br == 0) ? w11 : (br == 1) ? w21 : w31;
      const float* b1 = (br == 0) ? b11 : (br == 1) ? b21 : b31;
      const float* w2 = (br == 0) ? w12 : (br == 1) ? w22 : w32;
      const float* b2 = (br == 0) ? b12 : (br == 1) ? b22 : b32;
      __syncthreads();
      if (tid < 64) {
        float acc = b1[c];
        for (int m = 0; m < 64; ++m) acc = fmaf(w1[c * 64 + m], Rt[m], acc);
        A[c] = acc;
      }
      __syncthreads();
      if (tid < 64) {
        float acc = b2[c];
        for (int m = 0; m < 64; ++m) acc = fmaf(w2[c * 64 + m], A[m], acc);
        X2[br][c] = acc;
      }
    }
    __syncthreads();
    if (tid < 64) {
      float acc = 0.f;
      for (int m = 0; m < 64; ++m) acc = fmaf(fc_w[c * 320 + m],       Rt[m],    acc);
      for (int m = 0; m < 64; ++m) acc = fmaf(fc_w[c * 320 + 64 + m],  X2[0][m], acc);
      for (int m = 0; m < 64; ++m) acc = fmaf(fc_w[c * 320 + 128 + m], X2[1][m], acc);
      for (int m = 0; m < 64; ++m) acc = fmaf(fc_w[c * 320 + 192 + m], X2[2][m], acc);
      T4[v * 64 + c] = acc;
    }
  } else {
    if (tid < 64) rt_ext[23 * 64 + tid] = -1e30f;   // maxpool -inf pad row
    const int m = tid & 63, c0 = (tid >> 6) * 16;
    float acc[16];
    #pragma unroll
    for (int r = 0; r < 16; ++r) acc[r] = 0.f;
    for (int q = 0; q < 64; ++q) {
      const float w = c41_w[q * 64 + m];
      #pragma unroll
      for (int r = 0; r < 16; ++r)
        acc[r] = fmaf(fc_w[(c0 + r) * 320 + 256 + q], w, acc[r]);
    }
    #pragma unroll
    for (int r = 0; r < 16; ++r) W5[(c0 + r) * 64 + m] = acc[r];
    if (tid < 64) {
      float a2 = fc_b[tid];
      for (int q = 0; q < 64; ++q) a2 = fmaf(fc_w[tid * 320 + 256 + q], c41_b[q], a2);
      bias_fc[tid] = a2;
    }
  }
}

// ---------------------------------------------------------------------------
// tab_T5G: blocks 0..3 = one cp1 k-slice each (staged in LDS, conflict-free):
//   T5[v][k][o] and G[k][m][o]. Block 4: bb.
// ---------------------------------------------------------------------------
__global__ void __launch_bounds__(256)
tab_T5G(const float* __restrict__ cp1_w, const float* __restrict__ cp1_b,
        const float* __restrict__ T4, const float* __restrict__ W5,
        const float* __restrict__ bias_fc,
        float* __restrict__ T5, float* __restrict__ G, float* __restrict__ bb)
{
  const int k = blockIdx.x, tid = threadIdx.x;
  if (k < 4) {
    __shared__ float slice[64 * 65];  // [c][o] padded: +1 kills write conflicts
    __shared__ float W5l[64 * 64];    // [c][m]
    __shared__ float T4l[23 * 64];
    for (int i = tid; i < 4096; i += 256) {
      const int o = i >> 6, c = i & 63;
      slice[c * 65 + o] = cp1_w[o * 256 + c * 4 + k];
    }
    for (int i = tid; i < 4096; i += 256) W5l[i] = W5[i];
    for (int i = tid; i < 1472; i += 256) T4l[i] = T4[i];
    __syncthreads();
    for (int i = tid; i < 1472; i += 256) {
      const int v = i >> 6, o = i & 63;       // v uniform per 64-group
      float acc = 0.f;
      for (int c = 0; c < 64; ++c)
        acc = fmaf(slice[c * 65 + o], T4l[v * 64 + c], acc);  // bcast T4l
      T5[v * 256 + k * 64 + o] = acc;
    }
    for (int i = tid; i < 4096; i += 256) {
      const int m = i >> 6, o = i & 63;       // m uniform per 64-group
      float acc = 0.f;
      for (int c = 0; c < 64; ++c)
        acc = fmaf(slice[c * 65 + o], W5l[c * 64 + m], acc);  // bcast W5l
      G[k * 4096 + m * 64 + o] = acc;
    }
  } else {
    if (tid < 64) {
      float acc = cp1_b[tid];
      for (int c = 0; c < 64; ++c) {
        const float* p = &cp1_w[tid * 256 + c * 4];
        acc = fmaf(p[0] + p[1] + p[2] + p[3], bias_fc[c], acc);
      }
      bb[tid] = acc;
    }
  }
}

// FP5[v3][k][o] = sum_m G[k][m][o] * max3(rt[a],rt[c],rt[d])[m], v3 base-24.
// One k-pair (h) per block; 32 v per block; 4-v register tiling per m.
__global__ void __launch_bounds__(256)
tab_FP5(const float* __restrict__ G, const float* __restrict__ rt_ext,
        float* __restrict__ FP5)
{
  __shared__ float Gl[2][64][64];   // 32KB: one k-pair of G
  __shared__ float rtl[24 * 64];    // 6KB
  const int tid = threadIdx.x, lane = tid & 63, wave = tid >> 6;
  const int h = blockIdx.x & 1;
  const int vbase = (blockIdx.x >> 1) * 32;
  for (int i = tid; i < 1536; i += 256) rtl[i] = rt_ext[i];
  for (int i = tid; i < 8192; i += 256) ((float*)Gl)[i] = G[h * 8192 + i];
  __syncthreads();
  for (int g = 0; g < 2; ++g) {
    const int j0 = vbase + wave * 8 + g * 4;
    float p[4];
    #pragma unroll
    for (int r = 0; r < 4; ++r) {
      const int v = j0 + r;
      const int a = v / 576, rem = v - a * 576, c = rem / 24, dd = rem - c * 24;
      p[r] = fmaxf(fmaxf(rtl[a * 64 + lane], rtl[c * 64 + lane]), rtl[dd * 64 + lane]);
    }
    float acc[4][2];
    #pragma unroll
    for (int r = 0; r < 4; ++r) { acc[r][0] = 0.f; acc[r][1] = 0.f; }
    #pragma unroll
    for (int m = 0; m < 64; ++m) {
      const float g0 = Gl[0][m][lane], g1 = Gl[1][m][lane];
      #pragma unroll
      for (int r = 0; r < 4; ++r) {
        const float pv = __shfl(p[r], m);
        acc[r][0] = fmaf(g0, pv, acc[r][0]);
        acc[r][1] = fmaf(g1, pv, acc[r][1]);
      }
    }
    #pragma unroll
    for (int r = 0; r < 4; ++r) {
      const int v = j0 + r;
      FP5[v * 256 + (2 * h + 0) * 64 + lane] = acc[r][0];
      FP5[v * 256 + (2 * h + 1) * 64 + lane] = acc[r][1];
    }
  }
}

// ---------------------------------------------------------------------------
// Main fused kernel. One block (512 thr = 8 waves) per batch element.
// R11 diagnosis: VALU/trans-bound with LDS-pipe tax. This version:
//  - kx stride 65 -> 68 (17x16B aligned): krow merges to ds_read_b128
//  - score loop q-OUTER: krow/wa reads hoisted to q-level (480 -> 192 b128/wave)
// ---------------------------------------------------------------------------
__global__ void __launch_bounds__(512)
k_main(const int* __restrict__ x,
       const float* __restrict__ wt, const float* __restrict__ wx,
       const float* __restrict__ bh, const float* __restrict__ wa,
       const float* __restrict__ T5, const float* __restrict__ FP5,
       const float* __restrict__ bb, float* __restrict__ vv)
{
  __shared__ int x_lds[304];
  __shared__ __align__(16) float a_in_lds[75 * 64];   // 19200 B
  __shared__ __align__(16) float qt_lds[75 * 68];     // 20400 B
  __shared__ __align__(16) float kx_lds[75 * 68];     // 20400 B (aligned b128)
  __shared__ __align__(16) float tail_lds[75 * 12];   // 3600 B
  __shared__ float wa_lds[64];                        // total 65072 B

  const int tid = threadIdx.x, lane = tid & 63, wave = tid >> 6;
  const int b = blockIdx.x;

  for (int i = tid; i < 300; i += 512) x_lds[i] = x[b * 300 + i];
  if (tid < 64) wa_lds[tid] = wa[tid];
  __syncthreads();

  // ---- a_in[t][o] = bb + sum_k T5[x_l][k] + FP5[trip_l][k]
  {
    const float bbv = bb[lane];
    for (int t = wave; t < 75; t += 8) {
      float acc = bbv;
      #pragma unroll
      for (int k = 0; k < 4; ++k) {
        const int l = 4 * t + k;
        const int xa = (l == 0) ? 23 : x_lds[l - 1];
        const int xd = (l == 299) ? 23 : x_lds[l + 1];
        const int trip = (xa * 576 + x_lds[l] * 24 + xd) * 256;
        acc += T5[x_lds[l] * 256 + k * 64 + lane];
        acc += FP5[trip + k * 64 + lane];
      }
      a_in_lds[t * 64 + lane] = acc;
    }
  }
  __syncthreads();

  // ---- fused matvec: qt=(a_in@wt.T+bh)*K, kx=(a_in@wx.T)*K; share a-loads
  {
    float qacc[10], kacc[10];
    #pragma unroll
    for (int r = 0; r < 10; ++r) { qacc[r] = 0.f; kacc[r] = 0.f; }
    for (int c = 0; c < 4; ++c) {
      const float4 t0 = *(const float4*)&wt[lane * 64 + 16 * c];
      const float4 t1 = *(const float4*)&wt[lane * 64 + 16 * c + 4];
      const float4 t2 = *(const float4*)&wt[lane * 64 + 16 * c + 8];
      const float4 t3 = *(const float4*)&wt[lane * 64 + 16 * c + 12];
      const float4 x0 = *(const float4*)&wx[lane * 64 + 16 * c];
      const float4 x1 = *(const float4*)&wx[lane * 64 + 16 * c + 4];
      const float4 x2 = *(const float4*)&wx[lane * 64 + 16 * c + 8];
      const float4 x3 = *(const float4*)&wx[lane * 64 + 16 * c + 12];
      #pragma unroll
      for (int r = 0; r < 10; ++r) {
        const int i = wave + 8 * r;
        if (i < 75) {
          const float* arow = &a_in_lds[i * 64 + 16 * c];
          const float4 a0 = *(const float4*)&arow[0];
          const float4 a1 = *(const float4*)&arow[4];
          const float4 a2 = *(const float4*)&arow[8];
          const float4 a3 = *(const float4*)&arow[12];
          float q = qacc[r], kk = kacc[r];
          q = fmaf(t0.x, a0.x, q); q = fmaf(t0.y, a0.y, q);
          q = fmaf(t0.z, a0.z, q); q = fmaf(t0.w, a0.w, q);
          q = fmaf(t1.x, a1.x, q); q = fmaf(t1.y, a1.y, q);
          q = fmaf(t1.z, a1.z, q); q = fmaf(t1.w, a1.w, q);
          q = fmaf(t2.x, a2.x, q); q = fmaf(t2.y, a2.y, q);
          q = fmaf(t2.z, a2.z, q); q = fmaf(t2.w, a2.w, q);
          q = fmaf(t3.x, a3.x, q); q = fmaf(t3.y, a3.y, q);
          q = fmaf(t3.z, a3.z, q); q = fmaf(t3.w, a3.w, q);
          kk = fmaf(x0.x, a0.x, kk); kk = fmaf(x0.y, a0.y, kk);
          kk = fmaf(x0.z, a0.z, kk); kk = fmaf(x0.w, a0.w, kk);
          kk = fmaf(x1.x, a1.x, kk); kk = fmaf(x1.y, a1.y, kk);
          kk = fmaf(x1.z, a1.z, kk); kk = fmaf(x1.w, a1.w, kk);
          kk = fmaf(x2.x, a2.x, kk); kk = fmaf(x2.y, a2.y, kk);
          kk = fmaf(x2.z, a2.z, kk); kk = fmaf(x2.w, a2.w, kk);
          kk = fmaf(x3.x, a3.x, kk); kk = fmaf(x3.y, a3.y, kk);
          kk = fmaf(x3.z, a3.z, kk); kk = fmaf(x3.w, a3.w, kk);
          qacc[r] = q; kacc[r] = kk;
        }
      }
    }
    const float bhv = bh[lane];
    #pragma unroll
    for (int r = 0; r < 10; ++r) {
      const int i = wave + 8 * r;
      if (i < 75) {
        qt_lds[i * 68 + lane] = (qacc[r] + bhv) * K_C2LOG2E;
        kx_lds[i * 68 + lane] = kacc[r] * K_C2LOG2E;
      }
    }
  }
  __syncthreads();

  // ---- tail scores: S[i][64+jt], one lane per cell, bank-staggered d.
  for (int idx = tid; idx < 825; idx += 512) {
    const int i = idx / 11, jt = idx - i * 11;
    const float* qrow = &qt_lds[i * 68];
    const float* krow = &kx_lds[(64 + jt) * 68];
    float S = 0.f;
    #pragma unroll 8
    for (int dd = 0; dd < 64; ++dd) {
      const int d = (dd + lane) & 63;
      const float r = frcp(1.f + fexp2(qrow[d] + krow[d]));
      S = fmaf(wa_lds[d], r, S);
    }
    tail_lds[i * 12 + jt] = S;
  }
  __syncthreads();

  // ---- score loop, q OUTER: krow/wa read once per q (b128), qt per (q,r)
  float S1[10];
  #pragma unroll
  for (int r = 0; r < 10; ++r) S1[r] = 0.f;
  #pragma unroll
  for (int q = 0; q < 16; ++q) {
    const float4 k4 = *(const float4*)&kx_lds[lane * 68 + 4 * q];
    const float4 w4 = *(const float4*)&wa_lds[4 * q];
    #pragma unroll
    for (int r = 0; r < 10; ++r) {
      const int i = wave + 8 * r;
      if (i < 75) {
        const float4 q4 = *(const float4*)&qt_lds[i * 68 + 4 * q];  // bcast
        float rr;
        rr = frcp(1.f + fexp2(q4.x + k4.x)); S1[r] = fmaf(w4.x, rr, S1[r]);
        rr = frcp(1.f + fexp2(q4.y + k4.y)); S1[r] = fmaf(w4.y, rr, S1[r]);
        rr = frcp(1.f + fexp2(q4.z + k4.z)); S1[r] = fmaf(w4.z, rr, S1[r]);
        rr = frcp(1.f + fexp2(q4.w + k4.w)); S1[r] = fmaf(w4.w, rr, S1[r]);
      }
    }
  }

  // ---- softmax per wave-row -> probs in static regs
  float a1r[10], a2r[10];
  #pragma unroll
  for (int r = 0; r < 10; ++r) { a1r[r] = 0.f; a2r[r] = 0.f; }
  #pragma unroll
  for (int r = 0; r < 10; ++r) {
    const int i = wave + 8 * r;
    if (i < 75) {
      const float z1 = S1[r] * (-K_C2LOG2E);
      const float zt = (lane < 11) ? tail_lds[i * 12 + lane] * (-K_C2LOG2E) : -1e30f;
      float m = fmaxf(z1, zt);
      #pragma unroll
      for (int off = 32; off; off >>= 1) m = fmaxf(m, __shfl_xor(m, off));
      const float p1 = fexp2(z1 - m);
      const float p2 = (lane < 11) ? fexp2(zt - m) : 0.f;
      float s = p1 + p2;
      #pragma unroll
      for (int off = 32; off; off >>= 1) s += __shfl_xor(s, off);
      const float inv = frcp(s);
      a1r[r] = p1 * inv;
      a2r[r] = p2 * inv;
    }
  }

  // ---- PV outer-j: 1 LDS read per j + readlane broadcasts (VALU pipe)
  {
    float acc[10];
    #pragma unroll
    for (int r = 0; r < 10; ++r) acc[r] = 0.f;
    for (int j = 0; j < 64; ++j) {          // j uniform -> readlane legal
      const float ajo = a_in_lds[j * 64 + lane];
      #pragma unroll
      for (int r = 0; r < 10; ++r)
        acc[r] = fmaf(rdlanef(a1r[r], j), ajo, acc[r]);
    }
    for (int j = 0; j < 11; ++j) {
      const float ajo = a_in_lds[(64 + j) * 64 + lane];
      #pragma unroll
      for (int r = 0; r < 10; ++r)
        acc[r] = fmaf(rdlanef(a2r[r], j), ajo, acc[r]);
    }
    #pragma unroll
    for (int r = 0; r < 10; ++r) {
      const int i = wave + 8 * r;
      if (i < 75) vv[b * 4800 + i * 64 + lane] = fmaxf(acc[r], 0.f);  // relu
    }
  }
}

// ---------------------------------------------------------------------------
// Tail (R8 version, reverted): cp2 (k=5,s=5) -> [960] -> m1+relu -> m2.
// 2 batches per block; o=idx/15 keeps cp2_w reads quasi-broadcast and vv_lds
// reads 15-address/15-bank broadcasts; m1_w loads shared across the 2 batches.
// ---------------------------------------------------------------------------
__global__ void __launch_bounds__(256)
k_tail(const float* __restrict__ vv,
       const float* __restrict__ cp2_w, const float* __restrict__ cp2_b,
       const float* __restrict__ m1_w, const float* __restrict__ m1_b,
       const float* __restrict__ m2_w, const float* __restrict__ m2_b,
       float* __restrict__ out)
{
  __shared__ __align__(16) float vv_lds[75 * 65];  // stride-65 pad
  __shared__ float g_lds[2][960];
  __shared__ float y_lds[2][100];
  const int tid = threadIdx.x, lane = tid & 63, wave = tid >> 6;
  const int b0 = blockIdx.x * 2;

  for (int q = 0; q < 2; ++q) {
    const int b = b0 + q;
    __syncthreads();
    for (int idx = tid; idx < 4800; idx += 256) {
      const int i = idx >> 6, d = idx & 63;
      vv_lds[i * 65 + d] = vv[b * 4800 + idx];
    }
    __syncthreads();
    for (int idx = tid; idx < 960; idx += 256) {
      const int o = idx / 15, s = idx % 15;
      float acc = cp2_b[o];
      for (int c = 0; c < 64; ++c) {
        const float* wrow = &cp2_w[(o * 64 + c) * 5];
        const float* vrow = &vv_lds[5 * s * 65 + c];
        #pragma unroll
        for (int k = 0; k < 5; ++k)
          acc = fmaf(wrow[k], vrow[k * 65], acc);
      }
      g_lds[q][idx] = acc;  // idx == o*15 + s: matches reshape order
    }
  }
  __syncthreads();

  for (int u = wave; u < 100; u += 4) {
    float acc0 = 0.f, acc1 = 0.f;
    #pragma unroll
    for (int it = 0; it < 15; ++it) {
      const int n = it * 64 + lane;
      const float w = m1_w[u * 960 + n];
      acc0 = fmaf(w, g_lds[0][n], acc0);
      acc1 = fmaf(w, g_lds[1][n], acc1);
    }
    #pragma unroll
    for (int off = 32; off; off >>= 1) {
      acc0 += __shfl_xor(acc0, off);
      acc1 += __shfl_xor(acc1, off);
    }
    if (lane == 0) {
      const float mb = m1_b[u];
      y_lds[0][u] = fmaxf(acc0 + mb, 0.f);
      y_lds[1][u] = fmaxf(acc1 + mb, 0.f);
    }
  }
  __syncthreads();
  if (wave < 2) {
    const int q = wave;
    float s = y_lds[q][lane] * m2_w[lane];
    if (lane < 36) s = fmaf(y_lds[q][lane + 64], m2_w[lane + 64], s);
    #pragma unroll
    for (int off = 32; off; off >>= 1) s += __shfl_xor(s, off);
    if (lane == 0) out[b0 + q] = s + m2_b[0];
  }
}

// ---------------------------------------------------------------------------
extern "C" void kernel_launch(void* const* d_in, const int* in_sizes, int n_in,
                              void* d_out, int out_size, void* d_ws, size_t ws_size,
                              hipStream_t stream) {
  (void)in_sizes; (void)n_in; (void)out_size; (void)ws_size;
  const int*   x     = (const int*)  d_in[0];
  const float* emb   = (const float*)d_in[1];
  const float* dr_w  = (const float*)d_in[2];
  const float* dr_b  = (const float*)d_in[3];
  const float* c1_w  = (const float*)d_in[4];
  const float* c1_b  = (const float*)d_in[5];
  const float* c11_w = (const float*)d_in[6];
  const float* c11_b = (const float*)d_in[7];
  const float* c12_w = (const float*)d_in[8];
  const float* c12_b = (const float*)d_in[9];
  const float* c21_w = (const float*)d_in[10];
  const float* c21_b = (const float*)d_in[11];
  const float* c22_w = (const float*)d_in[12];
  const float* c22_b = (const float*)d_in[13];
  const float* c31_w = (const float*)d_in[14];
  const float* c31_b = (const float*)d_in[15];
  const float* c32_w = (const float*)d_in[16];
  const float* c32_b = (const float*)d_in[17];
  const float* c41_w = (const float*)d_in[18];
  const float* c41_b = (const float*)d_in[19];
  const float* fc_w  = (const float*)d_in[20];
  const float* fc_b  = (const float*)d_in[21];
  const float* cp1_w = (const float*)d_in[22];
  const float* cp1_b = (const float*)d_in[23];
  const float* cp2_w = (const float*)d_in[24];
  const float* cp2_b = (const float*)d_in[25];
  const float* wt    = (const float*)d_in[26];
  const float* wx    = (const float*)d_in[27];
  const float* bh    = (const float*)d_in[28];
  const float* wa    = (const float*)d_in[29];
  // d_in[30] = ba: cancels in softmax, unused
  const float* m1_w  = (const float*)d_in[31];
  const float* m1_b  = (const float*)d_in[32];
  const float* m2_w  = (const float*)d_in[33];
  const float* m2_b  = (const float*)d_in[34];
  float* out = (float*)d_out;

  // workspace layout (floats)
  float* ws      = (float*)d_ws;
  float* rt_ext  = ws;                 // 24*64          = 1536
  float* T5      = ws + 1536;          // 23*4*64        = 5888
  float* bb      = ws + 7424;          // 64
  float* G       = ws + 7488;          // 4*64*64        = 16384
  float* bias_fc = ws + 23872;         // 64
  float* T4      = ws + 28352;         // 23*64          = 1472
  float* W5      = ws + 29824;         // 64*64          = 4096
  float* FP5     = ws + 33920;         // 13824*4*64     = 3538944
  float* vv      = ws + 3572864;       // 512*75*64      = 2457600  (total ~24.1 MB)

  prep1  <<<24, 256, 0, stream>>>(emb, dr_w, dr_b, c1_w, c1_b,
                                  c11_w, c11_b, c12_w, c12_b,
                                  c21_w, c21_b, c22_w, c22_b,
                                  c31_w, c31_b, c32_w, c32_b,
                                  fc_w, fc_b, c41_w, c41_b,
                                  rt_ext, T4, W5, bias_fc);
  tab_T5G<<<5, 256, 0, stream>>>(cp1_w, cp1_b, T4, W5, bias_fc, T5, G, bb);
  tab_FP5<<<864, 256, 0, stream>>>(G, rt_ext, FP5);
  k_main <<<512, 512, 0, stream>>>(x, wt, wx, bh, wa, T5, FP5, bb, vv);
  k_tail <<<256, 256, 0, stream>>>(vv, cp2_w, cp2_b, m1_w, m1_b, m2_w, m2_b, out);
}